// Round 7
// baseline (109.621 us; speedup 1.0000x reference)
//
#include <hip/hip_runtime.h>
#include <math.h>

typedef unsigned long long ull;

#define Bc 4
#define Nc 4000
#define Cc 80
#define Lc 81
#define NCc (Nc * Cc)            // 320000 per image
#define NBINS 4096
#define BINSHIFT 14
#define FLOORB 655               // bin(score=0.02): only hist-count above this
#define NREP 8
#define MCAP 2048
#define TARGET 1024
#define DET 100
#define MBLK 1000                // fused_main blocks per image (4 rows/block)
#define CB2 40                   // compact blocks per image (1024 thr, 1 uint4/thr)
#define BBOX_CLIPF 4.135166556742356f
#define BIN_BASE 0x3C000000u

// ---------- helpers ----------
__device__ __forceinline__ unsigned enc_f(float f) {
  unsigned u = __float_as_uint(f);
  return (u & 0x80000000u) ? ~u : (u | 0x80000000u);
}
__device__ __forceinline__ float dec_f(unsigned e) {
  unsigned u = (e & 0x80000000u) ? (e ^ 0x80000000u) : ~e;
  return __uint_as_float(u);
}

__device__ __forceinline__ void decode_box(const float* __restrict__ deltas,
                                           const float* __restrict__ props,
                                           int b, int i, float* o) {
  int n = i / Cc, c = i % Cc;
  int row = b * Nc + n;
  const float4 d = *reinterpret_cast<const float4*>(deltas + (size_t)row * (Cc * 4) + c * 4);
  const float4 p = *reinterpret_cast<const float4*>(props + (size_t)row * 4);
  float w = p.z - p.x, h = p.w - p.y;
  float cx = p.x + 0.5f * w, cy = p.y + 0.5f * h;
  float dw = fminf(d.z, BBOX_CLIPF), dh = fminf(d.w, BBOX_CLIPF);
  float pcx = d.x * w + cx, pcy = d.y * h + cy;
  float pw = expf(dw) * w, ph = expf(dh) * h;
  o[0] = pcx - 0.5f * pw;
  o[1] = pcy - 0.5f * ph;
  o[2] = pcx + 0.5f * pw;
  o[3] = pcy + 0.5f * ph;
}

// ---------- kernel 0: zero hist + cnt (524544 B = 32784 uint4) ----------
__global__ void __launch_bounds__(256)
zero_ws(uint4* __restrict__ p) {
  int i = blockIdx.x * 256 + threadIdx.x;
  if (i < 32784) p[i] = make_uint4(0u, 0u, 0u, 0u);
}

// ---------- kernel 1: fused softmax + scores + bins + floored hist + coord max ----------
__global__ void __launch_bounds__(256)
fused_main(const float* __restrict__ logits,
           const float* __restrict__ deltas,
           const float* __restrict__ props,
           float* __restrict__ rowmax,
           float* __restrict__ rowsum,
           unsigned short* __restrict__ msk16,
           unsigned* __restrict__ hist,
           unsigned* __restrict__ blkmax) {
  const int wv = threadIdx.x >> 6, lane = threadIdx.x & 63;
  const int row = blockIdx.x * 4 + wv;            // 0..15999
  const int b = row / Nc;                          // uniform per block (4000 % 4 == 0)
  const int rep = blockIdx.x & (NREP - 1);

  const float* p = logits + (size_t)row * Lc;
  float v1 = p[lane];
  float v2 = (lane < 17) ? p[64 + lane] : -INFINITY;
  float m = fmaxf(v1, v2);
  #pragma unroll
  for (int o = 32; o; o >>= 1) m = fmaxf(m, __shfl_xor(m, o));
  float e1 = expf(v1 - m);
  float e2 = (lane < 17) ? expf(v2 - m) : 0.0f;
  float s = e1 + e2;
  #pragma unroll
  for (int o = 32; o; o >>= 1) s += __shfl_xor(s, o);
  if (lane == 0) { rowmax[row] = m; rowsum[row] = s; }

  // channel c1 = lane needs exp(p[lane+1]-m); c2 = 64+lane needs exp(p[65+lane]-m)
  float e2_0 = __shfl(e2, 0);
  float sd1 = __shfl_down(e1, 1);
  float sc1e = (lane == 63) ? e2_0 : sd1;
  float sc2e = __shfl_down(e2, 1);                 // valid for lane<16
  float score1 = sc1e / s;
  float score2 = sc2e / s;

  const float* drow = deltas + (size_t)row * (Cc * 4);
  const float4 pr = *reinterpret_cast<const float4*>(props + (size_t)row * 4);
  float w = pr.z - pr.x, h = pr.w - pr.y;
  float cx = pr.x + 0.5f * w, cy = pr.y + 0.5f * h;

  // ---- pass 1: c = lane (0..63) ----
  float4 d1 = *reinterpret_cast<const float4*>(drow + lane * 4);
  float dw1 = fminf(d1.z, BBOX_CLIPF), dh1 = fminf(d1.w, BBOX_CLIPF);
  float pcx1 = d1.x * w + cx, pcy1 = d1.y * h + cy;
  float pw1 = expf(dw1) * w, ph1 = expf(dh1) * h;
  float b10 = pcx1 - 0.5f * pw1, b11 = pcy1 - 0.5f * ph1;
  float b12 = pcx1 + 0.5f * pw1, b13 = pcy1 + 0.5f * ph1;
  float area1 = (b13 - b11) * (b12 - b10);
  bool valid1 = (score1 > 0.01f) && (area1 > 0.1f);
  unsigned bits1 = __float_as_uint(score1);
  int bin1 = (int)((bits1 - BIN_BASE) >> BINSHIFT);
  bin1 = bin1 < 0 ? 0 : (bin1 > NBINS - 1 ? NBINS - 1 : bin1);
  msk16[(size_t)row * Cc + lane] = valid1 ? (unsigned short)(bin1 + 1) : (unsigned short)0;
  if (valid1 && bin1 >= FLOORB)
    atomicAdd(&hist[((rep * Bc + b) << 12) + bin1], 1u);
  float mc = fmaxf(fmaxf(b10, b11), fmaxf(b12, b13));

  // ---- pass 2: c = 64 + lane (lane < 16) ----
  if (lane < 16) {
    float4 d2 = *reinterpret_cast<const float4*>(drow + (64 + lane) * 4);
    float dw2 = fminf(d2.z, BBOX_CLIPF), dh2 = fminf(d2.w, BBOX_CLIPF);
    float pcx2 = d2.x * w + cx, pcy2 = d2.y * h + cy;
    float pw2 = expf(dw2) * w, ph2 = expf(dh2) * h;
    float b20 = pcx2 - 0.5f * pw2, b21 = pcy2 - 0.5f * ph2;
    float b22 = pcx2 + 0.5f * pw2, b23 = pcy2 + 0.5f * ph2;
    float area2 = (b23 - b21) * (b22 - b20);
    bool valid2 = (score2 > 0.01f) && (area2 > 0.1f);
    unsigned bits2 = __float_as_uint(score2);
    int bin2 = (int)((bits2 - BIN_BASE) >> BINSHIFT);
    bin2 = bin2 < 0 ? 0 : (bin2 > NBINS - 1 ? NBINS - 1 : bin2);
    msk16[(size_t)row * Cc + 64 + lane] = valid2 ? (unsigned short)(bin2 + 1) : (unsigned short)0;
    if (valid2 && bin2 >= FLOORB)
      atomicAdd(&hist[((rep * Bc + b) << 12) + bin2], 1u);
    mc = fmaxf(mc, fmaxf(fmaxf(b20, b21), fmaxf(b22, b23)));
  }

  // block-level coordinate max
  unsigned e = enc_f(mc);
  #pragma unroll
  for (int o = 32; o; o >>= 1) {
    unsigned other = __shfl_xor(e, o);
    e = e > other ? e : other;
  }
  __shared__ unsigned wmax[4];
  if (lane == 0) wmax[wv] = e;
  __syncthreads();
  if (threadIdx.x == 0) {
    unsigned m0 = wmax[0] > wmax[1] ? wmax[0] : wmax[1];
    unsigned m1 = wmax[2] > wmax[3] ? wmax[2] : wmax[3];
    blkmax[blockIdx.x] = m0 > m1 ? m0 : m1;
  }
}

// ---------- kernel 2: inline Tbin + compaction (recompute exact score bits) ----------
__global__ void __launch_bounds__(1024)
compact_kernel(const unsigned short* __restrict__ msk16,
               const float* __restrict__ logits,
               const float* __restrict__ rowmax,
               const float* __restrict__ rowsum,
               const unsigned* __restrict__ hist,
               unsigned* __restrict__ cnt,
               ull* __restrict__ keysg) {
  const int b = blockIdx.x / CB2;
  const int loc = blockIdx.x % CB2;
  const int tid = threadIdx.x;
  const int lane = tid & 63;
  __shared__ unsigned sc[1024];
  __shared__ int sh_Tbin;

  // --- phase A: every block computes the (identical) threshold bin ---
  unsigned hv[4];
  unsigned psum = 0;
  #pragma unroll
  for (int k = 0; k < 4; ++k) {
    int bin = tid * 4 + k;
    unsigned s = 0;
    #pragma unroll
    for (int r = 0; r < NREP; ++r) s += hist[((r * Bc + b) << 12) + bin];
    hv[k] = s;
    psum += s;
  }
  sc[tid] = psum;
  __syncthreads();
  for (int o = 1; o < 1024; o <<= 1) {
    unsigned v = (tid + o < 1024) ? sc[tid + o] : 0u;
    __syncthreads();
    sc[tid] += v;
    __syncthreads();
  }
  unsigned suf = sc[tid];
  unsigned sufn = (tid < 1023) ? sc[tid + 1] : 0u;
  if (tid == 0 && sc[0] < TARGET) sh_Tbin = 0;       // fallback: take all valid
  if (suf >= TARGET && sufn < TARGET) {              // unique crossing thread
    unsigned cum = sufn;
    int tb_found = -1;
    #pragma unroll
    for (int k = 3; k >= 0; --k) {
      if (tb_found < 0) {
        cum += hv[k];
        if (cum >= TARGET) tb_found = tid * 4 + k;
      }
    }
    int tb = tb_found;
    while (cum > MCAP) {                             // pathological-tie guard
      unsigned s = 0;
      for (int r = 0; r < NREP; ++r) s += hist[((r * Bc + b) << 12) + tb];
      cum -= s;
      ++tb;
    }
    sh_Tbin = tb;
  }
  __syncthreads();
  const int Tbin = sh_Tbin;

  // --- phase B: filter + scatter (wave-aggregated atomics) ---
  const int i8 = loc * 1024 + tid;
  uint4 v = make_uint4(0u, 0u, 0u, 0u);
  if (i8 < NCc / 8)
    v = reinterpret_cast<const uint4*>(msk16 + (size_t)b * NCc)[i8];
  unsigned ms[8];
  ms[0] = v.x & 0xFFFFu; ms[1] = v.x >> 16;
  ms[2] = v.y & 0xFFFFu; ms[3] = v.y >> 16;
  ms[4] = v.z & 0xFFFFu; ms[5] = v.z >> 16;
  ms[6] = v.w & 0xFFFFu; ms[7] = v.w >> 16;

  #pragma unroll
  for (int q = 0; q < 8; ++q) {
    unsigned mq = ms[q];
    bool pred = (mq != 0u) && ((int)(mq - 1u) >= Tbin);
    ull bal = __ballot(pred);
    if (bal) {
      int nsel = __popcll(bal);
      int leader = __ffsll(bal) - 1;
      unsigned base = 0;
      if (lane == leader) base = atomicAdd(&cnt[b * 16], (unsigned)nsel);
      base = __shfl(base, leader);
      if (pred) {
        unsigned pos = base + (unsigned)__popcll(bal & ((1ULL << lane) - 1));
        if (pos < MCAP) {
          int i = i8 * 8 + q;
          int n = i / Cc, c = i % Cc;
          int row = b * Nc + n;
          float lg = logits[(size_t)row * Lc + (c + 1)];
          float score = expf(lg - rowmax[row]) / rowsum[row];  // identical expr -> identical bits
          unsigned bits = __float_as_uint(score);
          keysg[(size_t)b * MCAP + pos] =
              ((ull)(0xFFFFFFFFu - bits) << 32) | (unsigned)i;
        }
      }
    }
  }
}

// ---------- kernel 3: fused counting-rank + suppression bitmask (orig order) ----------
__global__ void __launch_bounds__(1024)
rankmask_kernel(const ull* __restrict__ keysg,
                const unsigned* __restrict__ cnt,
                const unsigned* __restrict__ blkmax,
                const float* __restrict__ deltas,
                const float* __restrict__ props,
                ull* __restrict__ keysg2,
                unsigned* __restrict__ r16,
                ull* __restrict__ maskm) {
  const int b = blockIdx.x >> 6;        // 64 blocks per image
  const int chunk = blockIdx.x & 63;    // orig rows [chunk*32, chunk*32+32)
  const int tid = threadIdx.x;
  const int wv = tid >> 6, lane = tid & 63;
  __shared__ ull keys[MCAP];            // 16 KB
  __shared__ float4 cbx[MCAP];          // 32 KB (offset coords, orig order)
  __shared__ unsigned sred[1024];       // 4 KB
  __shared__ float sh_off;
  int S = (int)cnt[b * 16]; if (S > MCAP) S = MCAP;

  // off_scale from blkmax
  unsigned e = (tid < MBLK) ? blkmax[b * MBLK + tid] : 0u;
  sred[tid] = e;
  __syncthreads();
  #pragma unroll
  for (int o = 512; o; o >>= 1) {
    if (tid < o) { unsigned v2 = sred[tid + o]; if (v2 > sred[tid]) sred[tid] = v2; }
    __syncthreads();
  }
  if (tid == 0) sh_off = dec_f(sred[0]) + 1.0f;

  // load keys
  for (int i = tid; i < MCAP; i += 1024)
    keys[i] = keysg[(size_t)b * MCAP + i];     // >=S entries garbage, never compared
  __syncthreads();
  const float off_scale = sh_off;

  // decode all candidates into LDS (orig order)
  for (int s2 = tid; s2 < MCAP; s2 += 1024) {
    if (s2 < S) {
      unsigned i = (unsigned)keys[s2];
      float bb[4];
      decode_box(deltas, props, b, (int)i, bb);
      float o = (float)((int)(i % Cc) + 1) * off_scale;
      cbx[s2] = make_float4(bb[0] + o, bb[1] + o, bb[2] + o, bb[3] + o);
    }
  }
  __syncthreads();

  // counting-rank for this chunk's 32 orig rows -> scatter key + orig slot
  #pragma unroll
  for (int p2 = 0; p2 < 2; ++p2) {
    const int r = chunk * 32 + wv * 2 + p2;
    if (r < S) {
      const ull kr = keys[r];
      int rank = 0;
      #pragma unroll 8
      for (int step = 0; step < 32; ++step) {
        int j = step * 64 + lane;
        bool pred = (j < S) && (keys[j] < kr);
        rank += __popcll(__ballot(pred));
      }
      if (lane == 0) {
        keysg2[(size_t)b * MCAP + rank] = kr;
        r16[(size_t)b * MCAP + rank] = (unsigned)r;
      }
    }
  }

  // suppression bitmask for this chunk's 32 orig rows (orig-index space)
  for (int q = wv; q < 32 * 32; q += 16) {
    const int r = q >> 5, w = q & 31;
    const int i = chunk * 32 + r;
    const int j = w * 64 + lane;
    bool cond = false;
    if (i < S && j < S && j != i) {
      float4 bi = cbx[i];
      float4 bj = cbx[j];
      float ix1 = fmaxf(bi.x, bj.x), iy1 = fmaxf(bi.y, bj.y);
      float ix2 = fminf(bi.z, bj.z), iy2 = fminf(bi.w, bj.w);
      float inter = fmaxf(ix2 - ix1, 0.0f) * fmaxf(iy2 - iy1, 0.0f);
      float a1 = (bi.z - bi.x) * (bi.w - bi.y);
      float a2 = (bj.z - bj.x) * (bj.w - bj.y);
      cond = (inter / (a1 + a2 - inter)) > 0.5f;
    }
    ull word = __ballot(cond);
    if (lane == 0 && i < S)
      maskm[((size_t)b * MCAP + i) * 32 + w] = word;
  }
}

// ---------- kernel 4: serial greedy scan (rank order, orig-space mask) + output ----------
__global__ void __launch_bounds__(128)
scan_kernel(const ull* __restrict__ maskm,
            const ull* __restrict__ keysg2,
            const unsigned* __restrict__ r16,
            const unsigned* __restrict__ cnt,
            const float* __restrict__ deltas,
            const float* __restrict__ props,
            float* __restrict__ out) {
  const int b = blockIdx.x;
  const int tid = threadIdx.x;
  __shared__ unsigned r16s[MCAP];       // 8 KB (orig slot per rank, clamped)
  __shared__ int acc_list[DET];
  __shared__ int sh_acnt;
  int S = (int)cnt[b * 16]; if (S > MCAP) S = MCAP;

  for (int i = tid; i < MCAP; i += 128)
    r16s[i] = r16[(size_t)b * MCAP + i] & (MCAP - 1);   // clamp stale entries
  __syncthreads();

  if (tid < 64) {
    const int lane = tid & 63;
    const ull* mrow = maskm + (size_t)b * MCAP * 32 + (lane & 31);
    ull state = 0;                      // bit o set => orig slot o suppressed
    ull pf[8];
    #pragma unroll
    for (int u = 0; u < 8; ++u)
      pf[u] = mrow[(size_t)r16s[u] * 32];
    int acnt = 0;
    for (int j0 = 0; j0 < S && acnt < DET; j0 += 8) {
      ull cur[8];
      #pragma unroll
      for (int u = 0; u < 8; ++u) cur[u] = pf[u];
      #pragma unroll
      for (int u = 0; u < 8; ++u) {
        int nj = j0 + 8 + u; if (nj > MCAP - 1) nj = MCAP - 1;
        pf[u] = mrow[(size_t)r16s[nj] * 32];
      }
      #pragma unroll
      for (int u = 0; u < 8; ++u) {
        const int j = j0 + u;
        const int o = (int)r16s[j];
        ull aw = __shfl(state, o >> 6);
        bool alive = (j < S) && (acnt < DET) && !((aw >> (o & 63)) & 1ULL);
        if (alive) {
          state |= cur[u];
          if (lane == 0) acc_list[acnt] = j;
          ++acnt;
        }
      }
    }
    if (lane == 0) sh_acnt = acnt;
  }
  __syncthreads();

  const int acnt = sh_acnt;
  if (tid < DET) {
    float bb[4] = {0.f, 0.f, 0.f, 0.f};
    float sc2 = 0.f, lb = 0.f;
    if (tid < acnt) {
      const int j = acc_list[tid];
      ull key = keysg2[(size_t)b * MCAP + j];
      unsigned bits = 0xFFFFFFFFu - (unsigned)(key >> 32);
      unsigned i = (unsigned)key;
      decode_box(deltas, props, b, (int)i, bb);
      sc2 = __uint_as_float(bits);
      lb = (float)((int)(i % Cc) + 1);
    }
    float* ob = out + (size_t)b * DET * 4 + tid * 4;
    ob[0] = bb[0]; ob[1] = bb[1]; ob[2] = bb[2]; ob[3] = bb[3];
    out[Bc * DET * 4 + b * DET + tid] = sc2;
    out[Bc * DET * 4 + Bc * DET + b * DET + tid] = lb;
  }
}

// ---------- launch ----------
extern "C" void kernel_launch(void* const* d_in, const int* in_sizes, int n_in,
                              void* d_out, int out_size, void* d_ws, size_t ws_size,
                              hipStream_t stream) {
  const float* logits = (const float*)d_in[0];   // (B*N, 81)
  const float* deltas = (const float*)d_in[1];   // (B*N, 320)
  const float* props  = (const float*)d_in[2];   // (B, N, 4)
  float* out = (float*)d_out;

  char* ws = (char*)d_ws;
  // zeroed region: hist (NREP*Bc*NBINS*4 = 524288 B) + cnt (256 B)
  unsigned* hist   = (unsigned*)(ws + 0);            // [0, 524288)
  unsigned* cnt    = (unsigned*)(ws + 524288);       // [524288, 524544)
  ull* keysg       = (ull*)(ws + 524544);            // 65,536 B
  ull* keysg2      = (ull*)(ws + 590080);            // 65,536 B
  unsigned* r16    = (unsigned*)(ws + 655616);       // 32,768 B
  unsigned* blkmax = (unsigned*)(ws + 688384);       // Bc*MBLK*4 = 16,000 B
  float* rowmax    = (float*)(ws + 704384);          // 64,000 B
  float* rowsum    = (float*)(ws + 768384);          // 64,000 B
  unsigned short* msk16 = (unsigned short*)(ws + 832384);   // 2,560,000 B
  // maskm overlays msk16 (msk16 last read in compact; maskm written in rankmask)
  ull* maskm       = (ull*)(ws + 832384);            // 2,097,152 B

  zero_ws<<<129, 256, 0, stream>>>((uint4*)ws);
  fused_main<<<Bc * MBLK, 256, 0, stream>>>(logits, deltas, props,
                                            rowmax, rowsum, msk16, hist, blkmax);
  compact_kernel<<<Bc * CB2, 1024, 0, stream>>>(msk16, logits, rowmax, rowsum,
                                                hist, cnt, keysg);
  rankmask_kernel<<<Bc * 64, 1024, 0, stream>>>(keysg, cnt, blkmax, deltas, props,
                                                keysg2, r16, maskm);
  scan_kernel<<<Bc, 128, 0, stream>>>(maskm, keysg2, r16, cnt, deltas, props, out);
}

// Round 8
// 100.185 us; speedup vs baseline: 1.0942x; 1.0942x over previous
//
#include <hip/hip_runtime.h>
#include <math.h>

typedef unsigned long long ull;

#define Bc 4
#define Nc 4000
#define Cc 80
#define Lc 81
#define NCc (Nc * Cc)            // 320000 per image
#define NBINS 4096
#define BINSHIFT 14
#define FLOORB 655               // bin(score=0.02): only hist-count above this
#define NREP 8
#define MCAP 2048
#define TARGET 1024
#define DET 100
#define MBLK 1000                // fused_main blocks per image (4 rows/block)
#define CB2 40                   // compact blocks per image (1024 thr, 1 uint4/thr)
#define BBOX_CLIPF 4.135166556742356f
#define BIN_BASE 0x3C000000u

// ---------- helpers ----------
__device__ __forceinline__ unsigned enc_f(float f) {
  unsigned u = __float_as_uint(f);
  return (u & 0x80000000u) ? ~u : (u | 0x80000000u);
}
__device__ __forceinline__ float dec_f(unsigned e) {
  unsigned u = (e & 0x80000000u) ? (e ^ 0x80000000u) : ~e;
  return __uint_as_float(u);
}

__device__ __forceinline__ void decode_box(const float* __restrict__ deltas,
                                           const float* __restrict__ props,
                                           int b, int i, float* o) {
  int n = i / Cc, c = i % Cc;
  int row = b * Nc + n;
  const float4 d = *reinterpret_cast<const float4*>(deltas + (size_t)row * (Cc * 4) + c * 4);
  const float4 p = *reinterpret_cast<const float4*>(props + (size_t)row * 4);
  float w = p.z - p.x, h = p.w - p.y;
  float cx = p.x + 0.5f * w, cy = p.y + 0.5f * h;
  float dw = fminf(d.z, BBOX_CLIPF), dh = fminf(d.w, BBOX_CLIPF);
  float pcx = d.x * w + cx, pcy = d.y * h + cy;
  float pw = expf(dw) * w, ph = expf(dh) * h;
  o[0] = pcx - 0.5f * pw;
  o[1] = pcy - 0.5f * ph;
  o[2] = pcx + 0.5f * pw;
  o[3] = pcy + 0.5f * ph;
}

// ---------- kernel 0: zero hist + cnt (524544 B = 32784 uint4) ----------
__global__ void __launch_bounds__(256)
zero_ws(uint4* __restrict__ p) {
  int i = blockIdx.x * 256 + threadIdx.x;
  if (i < 32784) p[i] = make_uint4(0u, 0u, 0u, 0u);
}

// ---------- kernel 1: fused softmax + scores + bins + floored hist + coord max ----------
__global__ void __launch_bounds__(256)
fused_main(const float* __restrict__ logits,
           const float* __restrict__ deltas,
           const float* __restrict__ props,
           float* __restrict__ rowmax,
           float* __restrict__ rowsum,
           unsigned short* __restrict__ msk16,
           unsigned* __restrict__ hist,
           unsigned* __restrict__ blkmax) {
  const int wv = threadIdx.x >> 6, lane = threadIdx.x & 63;
  const int row = blockIdx.x * 4 + wv;            // 0..15999
  const int b = row / Nc;                          // uniform per block (4000 % 4 == 0)
  const int rep = blockIdx.x & (NREP - 1);

  const float* p = logits + (size_t)row * Lc;
  float v1 = p[lane];
  float v2 = (lane < 17) ? p[64 + lane] : -INFINITY;
  float m = fmaxf(v1, v2);
  #pragma unroll
  for (int o = 32; o; o >>= 1) m = fmaxf(m, __shfl_xor(m, o));
  float e1 = expf(v1 - m);
  float e2 = (lane < 17) ? expf(v2 - m) : 0.0f;
  float s = e1 + e2;
  #pragma unroll
  for (int o = 32; o; o >>= 1) s += __shfl_xor(s, o);
  if (lane == 0) { rowmax[row] = m; rowsum[row] = s; }

  // channel c1 = lane needs exp(p[lane+1]-m); c2 = 64+lane needs exp(p[65+lane]-m)
  float e2_0 = __shfl(e2, 0);
  float sd1 = __shfl_down(e1, 1);
  float sc1e = (lane == 63) ? e2_0 : sd1;
  float sc2e = __shfl_down(e2, 1);                 // valid for lane<16
  float score1 = sc1e / s;
  float score2 = sc2e / s;

  const float* drow = deltas + (size_t)row * (Cc * 4);
  const float4 pr = *reinterpret_cast<const float4*>(props + (size_t)row * 4);
  float w = pr.z - pr.x, h = pr.w - pr.y;
  float cx = pr.x + 0.5f * w, cy = pr.y + 0.5f * h;

  // ---- pass 1: c = lane (0..63) ----
  float4 d1 = *reinterpret_cast<const float4*>(drow + lane * 4);
  float dw1 = fminf(d1.z, BBOX_CLIPF), dh1 = fminf(d1.w, BBOX_CLIPF);
  float pcx1 = d1.x * w + cx, pcy1 = d1.y * h + cy;
  float pw1 = expf(dw1) * w, ph1 = expf(dh1) * h;
  float b10 = pcx1 - 0.5f * pw1, b11 = pcy1 - 0.5f * ph1;
  float b12 = pcx1 + 0.5f * pw1, b13 = pcy1 + 0.5f * ph1;
  float area1 = (b13 - b11) * (b12 - b10);
  bool valid1 = (score1 > 0.01f) && (area1 > 0.1f);
  unsigned bits1 = __float_as_uint(score1);
  int bin1 = (int)((bits1 - BIN_BASE) >> BINSHIFT);
  bin1 = bin1 < 0 ? 0 : (bin1 > NBINS - 1 ? NBINS - 1 : bin1);
  msk16[(size_t)row * Cc + lane] = valid1 ? (unsigned short)(bin1 + 1) : (unsigned short)0;
  if (valid1 && bin1 >= FLOORB)
    atomicAdd(&hist[((rep * Bc + b) << 12) + bin1], 1u);
  float mc = fmaxf(fmaxf(b10, b11), fmaxf(b12, b13));

  // ---- pass 2: c = 64 + lane (lane < 16) ----
  if (lane < 16) {
    float4 d2 = *reinterpret_cast<const float4*>(drow + (64 + lane) * 4);
    float dw2 = fminf(d2.z, BBOX_CLIPF), dh2 = fminf(d2.w, BBOX_CLIPF);
    float pcx2 = d2.x * w + cx, pcy2 = d2.y * h + cy;
    float pw2 = expf(dw2) * w, ph2 = expf(dh2) * h;
    float b20 = pcx2 - 0.5f * pw2, b21 = pcy2 - 0.5f * ph2;
    float b22 = pcx2 + 0.5f * pw2, b23 = pcy2 + 0.5f * ph2;
    float area2 = (b23 - b21) * (b22 - b20);
    bool valid2 = (score2 > 0.01f) && (area2 > 0.1f);
    unsigned bits2 = __float_as_uint(score2);
    int bin2 = (int)((bits2 - BIN_BASE) >> BINSHIFT);
    bin2 = bin2 < 0 ? 0 : (bin2 > NBINS - 1 ? NBINS - 1 : bin2);
    msk16[(size_t)row * Cc + 64 + lane] = valid2 ? (unsigned short)(bin2 + 1) : (unsigned short)0;
    if (valid2 && bin2 >= FLOORB)
      atomicAdd(&hist[((rep * Bc + b) << 12) + bin2], 1u);
    mc = fmaxf(mc, fmaxf(fmaxf(b20, b21), fmaxf(b22, b23)));
  }

  // block-level coordinate max
  unsigned e = enc_f(mc);
  #pragma unroll
  for (int o = 32; o; o >>= 1) {
    unsigned other = __shfl_xor(e, o);
    e = e > other ? e : other;
  }
  __shared__ unsigned wmax[4];
  if (lane == 0) wmax[wv] = e;
  __syncthreads();
  if (threadIdx.x == 0) {
    unsigned m0 = wmax[0] > wmax[1] ? wmax[0] : wmax[1];
    unsigned m1 = wmax[2] > wmax[3] ? wmax[2] : wmax[3];
    blkmax[blockIdx.x] = m0 > m1 ? m0 : m1;
  }
}

// ---------- kernel 2: inline Tbin + compaction (recompute exact score bits) ----------
__global__ void __launch_bounds__(1024)
compact_kernel(const unsigned short* __restrict__ msk16,
               const float* __restrict__ logits,
               const float* __restrict__ rowmax,
               const float* __restrict__ rowsum,
               const unsigned* __restrict__ hist,
               unsigned* __restrict__ cnt,
               ull* __restrict__ keysg) {
  const int b = blockIdx.x / CB2;
  const int loc = blockIdx.x % CB2;
  const int tid = threadIdx.x;
  const int lane = tid & 63;
  __shared__ unsigned sc[1024];
  __shared__ int sh_Tbin;

  // --- phase A: every block computes the (identical) threshold bin ---
  unsigned hv[4];
  unsigned psum = 0;
  #pragma unroll
  for (int k = 0; k < 4; ++k) {
    int bin = tid * 4 + k;
    unsigned s = 0;
    #pragma unroll
    for (int r = 0; r < NREP; ++r) s += hist[((r * Bc + b) << 12) + bin];
    hv[k] = s;
    psum += s;
  }
  sc[tid] = psum;
  __syncthreads();
  for (int o = 1; o < 1024; o <<= 1) {
    unsigned v = (tid + o < 1024) ? sc[tid + o] : 0u;
    __syncthreads();
    sc[tid] += v;
    __syncthreads();
  }
  unsigned suf = sc[tid];
  unsigned sufn = (tid < 1023) ? sc[tid + 1] : 0u;
  if (tid == 0 && sc[0] < TARGET) sh_Tbin = 0;       // fallback: take all valid
  if (suf >= TARGET && sufn < TARGET) {              // unique crossing thread
    unsigned cum = sufn;
    int tb_found = -1;
    #pragma unroll
    for (int k = 3; k >= 0; --k) {
      if (tb_found < 0) {
        cum += hv[k];
        if (cum >= TARGET) tb_found = tid * 4 + k;
      }
    }
    int tb = tb_found;
    while (cum > MCAP) {                             // pathological-tie guard
      unsigned s = 0;
      for (int r = 0; r < NREP; ++r) s += hist[((r * Bc + b) << 12) + tb];
      cum -= s;
      ++tb;
    }
    sh_Tbin = tb;
  }
  __syncthreads();
  const int Tbin = sh_Tbin;

  // --- phase B: filter + scatter (wave-aggregated atomics) ---
  const int i8 = loc * 1024 + tid;
  uint4 v = make_uint4(0u, 0u, 0u, 0u);
  if (i8 < NCc / 8)
    v = reinterpret_cast<const uint4*>(msk16 + (size_t)b * NCc)[i8];
  unsigned ms[8];
  ms[0] = v.x & 0xFFFFu; ms[1] = v.x >> 16;
  ms[2] = v.y & 0xFFFFu; ms[3] = v.y >> 16;
  ms[4] = v.z & 0xFFFFu; ms[5] = v.z >> 16;
  ms[6] = v.w & 0xFFFFu; ms[7] = v.w >> 16;

  #pragma unroll
  for (int q = 0; q < 8; ++q) {
    unsigned mq = ms[q];
    bool pred = (mq != 0u) && ((int)(mq - 1u) >= Tbin);
    ull bal = __ballot(pred);
    if (bal) {
      int nsel = __popcll(bal);
      int leader = __ffsll(bal) - 1;
      unsigned base = 0;
      if (lane == leader) base = atomicAdd(&cnt[b * 16], (unsigned)nsel);
      base = __shfl(base, leader);
      if (pred) {
        unsigned pos = base + (unsigned)__popcll(bal & ((1ULL << lane) - 1));
        if (pos < MCAP) {
          int i = i8 * 8 + q;
          int n = i / Cc, c = i % Cc;
          int row = b * Nc + n;
          float lg = logits[(size_t)row * Lc + (c + 1)];
          float score = expf(lg - rowmax[row]) / rowsum[row];  // identical expr -> identical bits
          unsigned bits = __float_as_uint(score);
          keysg[(size_t)b * MCAP + pos] =
              ((ull)(0xFFFFFFFFu - bits) << 32) | (unsigned)i;
        }
      }
    }
  }
}

// ---------- kernel 3: counting-rank + rank-ordered key/box scatter ----------
__global__ void __launch_bounds__(1024)
rankscatter_kernel(const ull* __restrict__ keysg,
                   const unsigned* __restrict__ cnt,
                   const unsigned* __restrict__ blkmax,
                   const float* __restrict__ deltas,
                   const float* __restrict__ props,
                   ull* __restrict__ keysg2,
                   float4* __restrict__ boxesg) {
  const int b = blockIdx.x >> 6;        // 64 blocks per image
  const int chunk = blockIdx.x & 63;    // orig rows [chunk*32, chunk*32+32)
  const int tid = threadIdx.x;
  const int wv = tid >> 6, lane = tid & 63;
  __shared__ ull keys[MCAP];            // 16 KB
  __shared__ unsigned sred[1024];       // 4 KB
  __shared__ float sh_off;
  __shared__ int sh_rank[32];
  __shared__ ull sh_key[32];
  int S = (int)cnt[b * 16]; if (S > MCAP) S = MCAP;

  // off_scale from blkmax
  unsigned e = (tid < MBLK) ? blkmax[b * MBLK + tid] : 0u;
  sred[tid] = e;
  __syncthreads();
  #pragma unroll
  for (int o = 512; o; o >>= 1) {
    if (tid < o) { unsigned v2 = sred[tid + o]; if (v2 > sred[tid]) sred[tid] = v2; }
    __syncthreads();
  }
  if (tid == 0) sh_off = dec_f(sred[0]) + 1.0f;

  // load keys (entries >= S are garbage, never compared)
  for (int i = tid; i < MCAP; i += 1024)
    keys[i] = keysg[(size_t)b * MCAP + i];
  __syncthreads();

  // counting-rank this chunk's 32 orig rows (2 per wave)
  #pragma unroll
  for (int p2 = 0; p2 < 2; ++p2) {
    const int rloc = wv * 2 + p2;
    const int r = chunk * 32 + rloc;
    if (r < S) {
      const ull kr = keys[r];
      int rank = 0;
      #pragma unroll 8
      for (int step = 0; step < 32; ++step) {
        int j = step * 64 + lane;
        bool pred = (j < S) && (keys[j] < kr);
        rank += __popcll(__ballot(pred));
      }
      if (lane == 0) { sh_rank[rloc] = rank; sh_key[rloc] = kr; }
    } else if (lane == 0) {
      sh_rank[rloc] = -1;
    }
  }
  __syncthreads();

  // parallel decode + scatter (32 threads)
  if (tid < 32) {
    int rank = sh_rank[tid];
    if (rank >= 0) {
      ull kr = sh_key[tid];
      unsigned i = (unsigned)kr;
      float bb[4];
      decode_box(deltas, props, b, (int)i, bb);
      float o = (float)((int)(i % Cc) + 1) * sh_off;
      keysg2[(size_t)b * MCAP + rank] = kr;
      boxesg[(size_t)b * MCAP + rank] =
          make_float4(bb[0] + o, bb[1] + o, bb[2] + o, bb[3] + o);
    }
  }
}

// ---------- kernel 4: single-wave greedy NMS over rank-sorted boxes + output ----------
__global__ void __launch_bounds__(64)
nms_out_kernel(const ull* __restrict__ keysg2,
               const float4* __restrict__ boxesg,
               const unsigned* __restrict__ cnt,
               const float* __restrict__ deltas,
               const float* __restrict__ props,
               float* __restrict__ out) {
  const int b = blockIdx.x;
  const int lane = threadIdx.x;          // one wave per image
  __shared__ float4 chb[128];
  __shared__ ull chk[128];
  __shared__ ull acc_keys[DET];
  int S = (int)cnt[b * 16]; if (S > MCAP) S = MCAP;

  float4 a1 = make_float4(0.f, 0.f, 0.f, 0.f);
  float4 a2 = a1;                        // accepted slots: lane, 64+lane
  int acnt = 0;

  for (int base = 0; base < S && acnt < DET; base += 128) {
    int lim = S - base; if (lim > 128) lim = 128;
    #pragma unroll
    for (int u = 0; u < 2; ++u) {
      int idx = lane + u * 64;
      if (idx < lim) {
        chb[idx] = boxesg[(size_t)b * MCAP + base + idx];
        chk[idx] = keysg2[(size_t)b * MCAP + base + idx];
      }
    }
    __syncthreads();
    for (int jj = 0; jj < lim && acnt < DET; ++jj) {
      float4 bj = chb[jj];               // broadcast
      int sup = 0;
      if (lane < acnt) {
        float ix1 = fmaxf(bj.x, a1.x), iy1 = fmaxf(bj.y, a1.y);
        float ix2 = fminf(bj.z, a1.z), iy2 = fminf(bj.w, a1.w);
        float inter = fmaxf(ix2 - ix1, 0.0f) * fmaxf(iy2 - iy1, 0.0f);
        float ar1 = (bj.z - bj.x) * (bj.w - bj.y);
        float ar2 = (a1.z - a1.x) * (a1.w - a1.y);
        sup = (inter / (ar1 + ar2 - inter)) > 0.5f;
      }
      if (64 + lane < acnt) {
        float ix1 = fmaxf(bj.x, a2.x), iy1 = fmaxf(bj.y, a2.y);
        float ix2 = fminf(bj.z, a2.z), iy2 = fminf(bj.w, a2.w);
        float inter = fmaxf(ix2 - ix1, 0.0f) * fmaxf(iy2 - iy1, 0.0f);
        float ar1 = (bj.z - bj.x) * (bj.w - bj.y);
        float ar2 = (a2.z - a2.x) * (a2.w - a2.y);
        sup |= (inter / (ar1 + ar2 - inter)) > 0.5f;
      }
      if (!__any(sup)) {
        if (lane == acnt) a1 = bj;
        if (64 + lane == acnt) a2 = bj;
        if (lane == 0) acc_keys[acnt] = chk[jj];
        ++acnt;
      }
    }
    __syncthreads();
  }
  __syncthreads();

  #pragma unroll
  for (int u = 0; u < 2; ++u) {
    int t = lane + u * 64;
    if (t < DET) {
      float bb[4] = {0.f, 0.f, 0.f, 0.f};
      float sc2 = 0.f, lb = 0.f;
      if (t < acnt) {
        ull key = acc_keys[t];
        unsigned bits = 0xFFFFFFFFu - (unsigned)(key >> 32);
        unsigned i = (unsigned)key;
        decode_box(deltas, props, b, (int)i, bb);
        sc2 = __uint_as_float(bits);
        lb = (float)((int)(i % Cc) + 1);
      }
      float* ob = out + (size_t)b * DET * 4 + t * 4;
      ob[0] = bb[0]; ob[1] = bb[1]; ob[2] = bb[2]; ob[3] = bb[3];
      out[Bc * DET * 4 + b * DET + t] = sc2;
      out[Bc * DET * 4 + Bc * DET + b * DET + t] = lb;
    }
  }
}

// ---------- launch ----------
extern "C" void kernel_launch(void* const* d_in, const int* in_sizes, int n_in,
                              void* d_out, int out_size, void* d_ws, size_t ws_size,
                              hipStream_t stream) {
  const float* logits = (const float*)d_in[0];   // (B*N, 81)
  const float* deltas = (const float*)d_in[1];   // (B*N, 320)
  const float* props  = (const float*)d_in[2];   // (B, N, 4)
  float* out = (float*)d_out;

  char* ws = (char*)d_ws;
  // zeroed region: hist (NREP*Bc*NBINS*4 = 524288 B) + cnt (256 B)
  unsigned* hist   = (unsigned*)(ws + 0);            // [0, 524288)
  unsigned* cnt    = (unsigned*)(ws + 524288);       // [524288, 524544)
  ull* keysg       = (ull*)(ws + 524544);            // 65,536 B
  ull* keysg2      = (ull*)(ws + 590080);            // 65,536 B
  float4* boxesg   = (float4*)(ws + 655616);         // 131,072 B (16B aligned)
  unsigned* blkmax = (unsigned*)(ws + 786688);       // Bc*MBLK*4 = 16,000 B
  float* rowmax    = (float*)(ws + 802688);          // 64,000 B
  float* rowsum    = (float*)(ws + 866688);          // 64,000 B
  unsigned short* msk16 = (unsigned short*)(ws + 930688);   // 2,560,000 B

  zero_ws<<<129, 256, 0, stream>>>((uint4*)ws);
  fused_main<<<Bc * MBLK, 256, 0, stream>>>(logits, deltas, props,
                                            rowmax, rowsum, msk16, hist, blkmax);
  compact_kernel<<<Bc * CB2, 1024, 0, stream>>>(msk16, logits, rowmax, rowsum,
                                                hist, cnt, keysg);
  rankscatter_kernel<<<Bc * 64, 1024, 0, stream>>>(keysg, cnt, blkmax, deltas, props,
                                                   keysg2, boxesg);
  nms_out_kernel<<<Bc, 64, 0, stream>>>(keysg2, boxesg, cnt, deltas, props, out);
}